// Round 10
// baseline (387.853 us; speedup 1.0000x reference)
//
#include <hip/hip_runtime.h>
#include <hip/hip_cooperative_groups.h>
#include <hip/hip_bf16.h>
#include <math.h>

namespace cg = cooperative_groups;

#define BATCH 16
#define CH    256
#define HW    1024
#define NS    256
#define NH    16
#define DH    16

typedef __attribute__((ext_vector_type(8))) short short8v;
typedef __attribute__((ext_vector_type(4))) float float4v;

__device__ __forceinline__ unsigned short f2bf(float f) {
    return __builtin_bit_cast(unsigned short, __float2bfloat16(f));
}
__device__ __forceinline__ unsigned pack2(float lo, float hi) {
    return (unsigned)f2bf(lo) | ((unsigned)f2bf(hi) << 16);
}

// ---------------------------------------------------------------------------
// P0: prep unit. u<1024: weight repack (A-frag order). u>=1024: x -> xT bf16.
// ---------------------------------------------------------------------------
__device__ __forceinline__ void prep_unit(
    int blk, const float* __restrict__ wq, const float* __restrict__ wk,
    const float* __restrict__ wv, const float* __restrict__ wo,
    unsigned short* __restrict__ Wf,
    const float* __restrict__ x, unsigned short* __restrict__ xT)
{
    if (blk < 1024) {
        const float* W;
        switch (blk >> 8) {
            case 0: W = wq; break;
            case 1: W = wk; break;
            case 2: W = wv; break;
            default: W = wo; break;
        }
        int e = (blk & 255) * 256 + threadIdx.x;
        int i = e & 7, l = (e >> 3) & 63, kt = (e >> 9) & 7, ot = e >> 12;
        float v = W[(ot * 16 + (l & 15)) * 256 + kt * 32 + 8 * (l >> 4) + i];
        Wf[(blk >> 8) * 65536 + e] = f2bf(v);
    } else {
        int xb = blk - 1024;
        int b = xb >> 4, pblk = (xb >> 2) & 3, cblk = xb & 3;
        int p = pblk * 256 + threadIdx.x;
        const float* xp = x + (size_t)b * CH * HW + p;
        unsigned short* o = xT + ((size_t)b * HW + p) * CH;
        #pragma unroll
        for (int cc = 0; cc < 64; cc += 8) {
            int c0 = cblk * 64 + cc;
            short8v t;
            #pragma unroll
            for (int i = 0; i < 8; ++i) t[i] = (short)f2bf(xp[(size_t)(c0 + i) * HW]);
            *(short8v*)&o[c0] = t;
        }
    }
}

// ---------------------------------------------------------------------------
// GEMM unit (64x128 tile, register-direct, packed Wf).  MODE 0: Q, 1: KV, 2: O.
// ---------------------------------------------------------------------------
template<int P, int MODE>
__device__ __forceinline__ void gemm_unit(
    int ox, int py, int bz,
    const unsigned short* __restrict__ Wf, const unsigned short* __restrict__ XT,
    const float* __restrict__ bias, const float* __restrict__ bias2,
    float* __restrict__ outF, unsigned short* __restrict__ outB,
    unsigned short* __restrict__ outB2,
    const float* __restrict__ bn_g, const float* __restrict__ bn_b,
    const float* __restrict__ bn_m, const float* __restrict__ bn_v)
{
    const int b   = (MODE == 1) ? (bz & 15) : bz;
    const int mat = (MODE == 1) ? (bz >> 4) : 0;
    const unsigned short* Wfm = Wf + mat * 65536;

    const int t = threadIdx.x, lane = t & 63, wvi = t >> 6;
    const int g = lane >> 4, col = lane & 15;
    const int o0 = ox * 64;
    const int p0 = py * 128 + wvi * 32;
    const unsigned short* xb = XT + ((size_t)b * P + p0) * CH;

    float4v acc[4][2];
    #pragma unroll
    for (int mi = 0; mi < 4; ++mi)
        #pragma unroll
        for (int ni = 0; ni < 2; ++ni) {
            float4v z = {0.f, 0.f, 0.f, 0.f};
            acc[mi][ni] = z;
        }

    #pragma unroll
    for (int kt = 0; kt < 8; ++kt) {
        short8v af[4], bf[2];
        #pragma unroll
        for (int mi = 0; mi < 4; ++mi)
            af[mi] = *(const short8v*)&Wfm[((((ox * 4 + mi) * 8) + kt) * 64 + lane) * 8];
        #pragma unroll
        for (int ni = 0; ni < 2; ++ni)
            bf[ni] = *(const short8v*)&xb[(size_t)(ni * 16 + col) * CH + kt * 32 + 8 * g];
        #pragma unroll
        for (int mi = 0; mi < 4; ++mi)
            #pragma unroll
            for (int ni = 0; ni < 2; ++ni)
                acc[mi][ni] = __builtin_amdgcn_mfma_f32_16x16x32_bf16(
                    af[mi], bf[ni], acc[mi][ni], 0, 0, 0);
    }

    const float* bp = (MODE == 1 && mat == 1) ? bias2 : bias;
    #pragma unroll
    for (int mi = 0; mi < 4; ++mi) {
        const int ob = o0 + mi * 16 + 4 * g;
        float bs[4];
        #pragma unroll
        for (int ii = 0; ii < 4; ++ii) bs[ii] = bp[ob + ii];

        if (MODE == 2) {
            float sc[4], sh[4];
            #pragma unroll
            for (int ii = 0; ii < 4; ++ii) {
                int o = ob + ii;
                float s = bn_g[o] * rsqrtf(bn_v[o] + 1e-5f);
                sc[ii] = s;
                sh[ii] = bn_b[o] - bn_m[o] * s + bs[ii] * s;
            }
            #pragma unroll
            for (int ni = 0; ni < 2; ++ni) {
                int p = p0 + ni * 16 + col;
                #pragma unroll
                for (int ii = 0; ii < 4; ++ii)
                    outF[((size_t)(b * CH + ob + ii)) * P + p] =
                        acc[mi][ni][ii] * sc[ii] + sh[ii];
            }
        } else {
            #pragma unroll
            for (int ni = 0; ni < 2; ++ni) {
                int p = p0 + ni * 16 + col;
                float v0 = acc[mi][ni][0] + bs[0];
                float v1 = acc[mi][ni][1] + bs[1];
                float v2 = acc[mi][ni][2] + bs[2];
                float v3 = acc[mi][ni][3] + bs[3];
                if (MODE == 0) {
                    outF[((size_t)(b * CH + ob + 0)) * P + p] = v0;
                    outF[((size_t)(b * CH + ob + 1)) * P + p] = v1;
                    outF[((size_t)(b * CH + ob + 2)) * P + p] = v2;
                    outF[((size_t)(b * CH + ob + 3)) * P + p] = v3;
                    uint2 w;   // qT pre-scaled by 0.25 (exact pow2)
                    w.x = pack2(v0 * 0.25f, v1 * 0.25f);
                    w.y = pack2(v2 * 0.25f, v3 * 0.25f);
                    *(uint2*)&outB[((size_t)(b * P + p)) * CH + ob] = w;
                } else {
                    if (mat == 0) {
                        uint2 w;
                        w.x = pack2(v0, v1);
                        w.y = pack2(v2, v3);
                        *(uint2*)&outB[((size_t)(b * P + p)) * CH + ob] = w;
                    } else {
                        outB2[((size_t)(b * CH + ob + 0)) * P + p] = f2bf(v0);
                        outB2[((size_t)(b * CH + ob + 1)) * P + p] = f2bf(v1);
                        outB2[((size_t)(b * CH + ob + 2)) * P + p] = f2bf(v2);
                        outB2[((size_t)(b * CH + ob + 3)) * P + p] = f2bf(v3);
                    }
                }
            }
        }
    }
}

// ---------------------------------------------------------------------------
// P2: depthwise 9x9 conv unit (one (b,c) plane)
// ---------------------------------------------------------------------------
__device__ __forceinline__ void dwconv_unit(
    int bc, float* plane, float* kw,
    const float* __restrict__ q, const float* __restrict__ w,
    const float* __restrict__ bias, float* __restrict__ off)
{
    int c = bc & (CH - 1);
    int t = threadIdx.x;
    const float* qp = q + (size_t)bc * HW;
    #pragma unroll
    for (int j = t; j < HW; j += 256) plane[j] = qp[j];
    if (t < 81) kw[t] = w[c * 81 + t];
    __syncthreads();
    int hk = t >> 4, wk = t & 15;
    float s = bias[c];
    int yb = hk * 2 - 4, xb = wk * 2 - 4;
    #pragma unroll
    for (int dy = 0; dy < 9; ++dy) {
        int yy = yb + dy;
        if ((unsigned)yy < 32u) {
            #pragma unroll
            for (int dx = 0; dx < 9; ++dx) {
                int xx = xb + dx;
                if ((unsigned)xx < 32u) s += kw[dy * 9 + dx] * plane[yy * 32 + xx];
            }
        }
    }
    off[(size_t)bc * NS + t] = s;
    __syncthreads();   // protect plane reuse across grid-stride iterations
}

// ---------------------------------------------------------------------------
// P3: LN + GELU + proj + ref + tanh + bilinear sample unit (one (b,s))
// ---------------------------------------------------------------------------
__device__ __forceinline__ void block_reduce2(float& a, float& b, int t, float* sbuf)
{
    #pragma unroll
    for (int o = 32; o > 0; o >>= 1) {
        a += __shfl_down(a, o);
        b += __shfl_down(b, o);
    }
    int w = t >> 6;
    if ((t & 63) == 0) { sbuf[w * 2] = a; sbuf[w * 2 + 1] = b; }
    __syncthreads();
    a = sbuf[0] + sbuf[2] + sbuf[4] + sbuf[6];
    b = sbuf[1] + sbuf[3] + sbuf[5] + sbuf[7];
    __syncthreads();
}

__device__ __forceinline__ void lngs_unit(
    int bs, float* sbuf,
    const float* __restrict__ off, const float* __restrict__ ln_g,
    const float* __restrict__ ln_b, const float* __restrict__ pw,
    const float* __restrict__ x, unsigned short* __restrict__ xsT)
{
    int b = bs >> 8, s = bs & 255;
    int c = threadIdx.x;
    float v = off[((size_t)(b * CH + c)) * NS + s];
    float a = v, q2 = v * v;
    block_reduce2(a, q2, c, sbuf);
    float mean = a * (1.0f / 256.0f);
    float var  = q2 * (1.0f / 256.0f) - mean * mean;
    float xn = (v - mean) * rsqrtf(var + 1e-5f) * ln_g[c] + ln_b[c];
    float g = 0.5f * xn * (1.0f + erff(xn * 0.70710678118654752f));
    float d0 = g * pw[c];
    float d1 = g * pw[CH + c];
    block_reduce2(d0, d1, c, sbuf);

    int hk = s >> 4, wk = s & 15;
    float ry = ((hk + 0.5f) / 16.0f) * 2.0f - 1.0f;
    float rx = ((wk + 0.5f) / 16.0f) * 2.0f - 1.0f;
    float py = tanhf(d0 + ry);
    float px = tanhf(d1 + rx);

    float gx = (px + 1.0f) * 0.5f * 31.0f;
    float gy = (py + 1.0f) * 0.5f * 31.0f;
    float x0f = floorf(gx), y0f = floorf(gy);
    int ix = (int)x0f, iy = (int)y0f;
    float wx1 = gx - x0f, wx0 = 1.0f - wx1;
    float wy1 = gy - y0f, wy0 = 1.0f - wy1;
    const float* img = x + ((size_t)b * CH + c) * HW;
    float v00 = ((unsigned)iy < 32u && (unsigned)ix < 32u) ? img[iy * 32 + ix] : 0.0f;
    float v01 = ((unsigned)iy < 32u && (unsigned)(ix + 1) < 32u) ? img[iy * 32 + ix + 1] : 0.0f;
    float v10 = ((unsigned)(iy + 1) < 32u && (unsigned)ix < 32u) ? img[(iy + 1) * 32 + ix] : 0.0f;
    float v11 = ((unsigned)(iy + 1) < 32u && (unsigned)(ix + 1) < 32u) ? img[(iy + 1) * 32 + ix + 1] : 0.0f;
    float vv = wy0 * wx0 * v00 + wy0 * wx1 * v01 + wy1 * wx0 * v10 + wy1 * wx1 * v11;
    xsT[(size_t)bs * CH + c] = f2bf(vv);
}

// ---------------------------------------------------------------------------
// P5: MFMA attention unit (one (bh, mseg))
// ---------------------------------------------------------------------------
__device__ __forceinline__ void attn_unit(
    int u, short* Kp, short* Vsh, short* Ps,
    const unsigned short* __restrict__ qT, const unsigned short* __restrict__ kT,
    const unsigned short* __restrict__ vbf, unsigned short* __restrict__ aoT)
{
    const int bh   = u >> 2;
    const int mseg = u & 3;
    const int b = bh >> 4, h = bh & 15;

    const int tid  = threadIdx.x;
    const int lane = tid & 63;
    const int wvi  = tid >> 6;
    const int col  = lane & 15;
    const int g    = lane >> 4;

    for (int e = tid; e < 512; e += 256) {
        int t = e >> 5, l = e & 31, gg = l >> 4, c = l & 15;
        short8v kk = *(const short8v*)&kT[((size_t)(b * NS + 16 * t + c)) * CH + h * 16 + 8 * gg];
        *(short8v*)&Kp[(t * 32 + l) * 8] = kk;
    }
    if (tid == 0) {
        short8v z = {0, 0, 0, 0, 0, 0, 0, 0};
        *(short8v*)&Kp[16 * 32 * 8] = z;
    }
    {
        const unsigned short* Vb = vbf + ((size_t)(b * CH + h * 16)) * NS;
        int d = tid >> 4, n0 = (tid & 15) * 16;
        char* vb = (char*)Vsh;
        #pragma unroll
        for (int hh = 0; hh < 2; ++hh) {
            short8v pk = *(const short8v*)&Vb[(size_t)d * NS + n0 + 8 * hh];
            *(short8v*)(vb + ((d * 512 + (n0 + 8 * hh) * 2) ^ ((d & 7) << 4))) = pk;
        }
    }
    __syncthreads();

    const unsigned short* Qb = qT + (size_t)b * HW * CH + h * 16;
    unsigned short*       Ob = aoT + (size_t)b * HW * CH + h * 16;
    char* pbase = (char*)(Ps + wvi * 512);
    const char* kbase = (const char*)Kp + ((lane < 32) ? lane * 16 : 16 * 32 * 16);
    const int   kstep = (lane < 32) ? 512 : 0;

    for (int mt = 0; mt < 4; ++mt) {
        const int m0 = mseg * 256 + wvi * 64 + mt * 16;

        short8v qf = {0, 0, 0, 0, 0, 0, 0, 0};
        if (g < 2)
            qf = *(const short8v*)&Qb[(size_t)(m0 + col) * CH + 8 * g];

        float4v p[16];
        #pragma unroll
        for (int t = 0; t < 16; ++t) {
            short8v kf = *(const short8v*)(kbase + t * kstep);
            float4v z = {0.f, 0.f, 0.f, 0.f};
            p[t] = __builtin_amdgcn_mfma_f32_16x16x32_bf16(kf, qf, z, 0, 0, 0);
        }

        float mx4[16];
        #pragma unroll
        for (int t = 0; t < 16; ++t)
            mx4[t] = fmaxf(fmaxf(p[t][0], p[t][1]), fmaxf(p[t][2], p[t][3]));
        #pragma unroll
        for (int o = 8; o >= 1; o >>= 1)
            #pragma unroll
            for (int i = 0; i < 8; ++i)
                if (i < o) mx4[i] = fmaxf(mx4[i], mx4[i + o]);
        float mx = mx4[0];
        mx = fmaxf(mx, __shfl_xor(mx, 16));
        mx = fmaxf(mx, __shfl_xor(mx, 32));

        float s4[4] = {0.f, 0.f, 0.f, 0.f};
        #pragma unroll
        for (int t = 0; t < 16; ++t) {
            #pragma unroll
            for (int i = 0; i < 4; ++i) {
                float e = __expf(p[t][i] - mx);
                p[t][i] = e;
                s4[i] += e;
            }
        }
        float sum = (s4[0] + s4[1]) + (s4[2] + s4[3]);
        sum += __shfl_xor(sum, 16);
        sum += __shfl_xor(sum, 32);
        const float inv = 1.0f / sum;

        float4v acc = {0.f, 0.f, 0.f, 0.f};
        #pragma unroll
        for (int c = 0; c < 8; ++c) {
            #pragma unroll
            for (int pp = 0; pp < 2; ++pp) {
                float4v pv = p[2 * c + pp];
                uint2 wr;
                wr.x = pack2(pv[0], pv[1]);
                wr.y = pack2(pv[2], pv[3]);
                *(uint2*)(pbase + ((col * 64 + (16 * pp + 4 * g) * 2) ^ ((col & 7) << 4))) = wr;
            }
            short8v pf = *(const short8v*)(pbase + ((col * 64 + 16 * g) ^ ((col & 7) << 4)));
            short8v vf = *(const short8v*)((char*)Vsh + ((col * 512 + 64 * c + 16 * g) ^ ((col & 7) << 4)));
            acc = __builtin_amdgcn_mfma_f32_16x16x32_bf16(vf, pf, acc, 0, 0, 0);
        }

        uint2 w;
        w.x = pack2(acc[0] * inv, acc[1] * inv);
        w.y = pack2(acc[2] * inv, acc[3] * inv);
        *(uint2*)&Ob[(size_t)(m0 + col) * CH + 4 * g] = w;
    }
    __syncthreads();   // protect Kp/Vsh reuse across grid-stride iterations
}

// ---------------------------------------------------------------------------
// The persistent cooperative kernel: 7 phases, 6 grid syncs.
// ---------------------------------------------------------------------------
__global__ __launch_bounds__(256) void fused_k(
    const float* x, const float* wq, const float* bq,
    const float* off_dw_w, const float* off_dw_b,
    const float* ln_g, const float* ln_b, const float* off_pw_w,
    const float* wk, const float* bk, const float* wv, const float* bv,
    const float* wo, const float* bo,
    const float* bn_g, const float* bn_b, const float* bn_m, const float* bn_v,
    float* q, float* off, unsigned short* Wf, unsigned short* xT,
    unsigned short* qT, unsigned short* xsT, unsigned short* kT,
    unsigned short* vbf, unsigned short* aoT, float* out)
{
    cg::grid_group grid = cg::this_grid();
    __shared__ __align__(16) char smem[20496];
    const int nb = gridDim.x;
    const int bid = blockIdx.x;

    // P0: prep (1280 units)
    for (int u = bid; u < 1280; u += nb)
        prep_unit(u, wq, wk, wv, wo, Wf, x, xT);
    grid.sync();

    // P1: gemmQ (512 units)
    for (int u = bid; u < 512; u += nb)
        gemm_unit<HW, 0>(u & 3, (u >> 2) & 7, u >> 5, Wf, xT, bq, nullptr,
                         q, qT, nullptr, nullptr, nullptr, nullptr, nullptr);
    grid.sync();

    // P2: dwconv (4096 units)
    for (int u = bid; u < 4096; u += nb)
        dwconv_unit(u, (float*)smem, (float*)(smem + 16384),
                    q, off_dw_w, off_dw_b, off);
    grid.sync();

    // P3: lngs (4096 units)
    for (int u = bid; u < 4096; u += nb)
        lngs_unit(u, (float*)smem, off, ln_g, ln_b, off_pw_w, x, xsT);
    grid.sync();

    // P4: gemmKV (256 units)
    for (int u = bid; u < 256; u += nb)
        gemm_unit<NS, 1>(u & 3, (u >> 2) & 1, u >> 3, Wf + 65536, xsT, bk, bv,
                         nullptr, kT, vbf, nullptr, nullptr, nullptr, nullptr);
    grid.sync();

    // P5: attention (1024 units)
    for (int u = bid; u < 1024; u += nb)
        attn_unit(u, (short*)smem, (short*)(smem + 8208),
                  (short*)(smem + 16400), qT, kT, vbf, aoT);
    grid.sync();

    // P6: gemmO (512 units)
    for (int u = bid; u < 512; u += nb)
        gemm_unit<HW, 2>(u & 3, (u >> 2) & 7, u >> 5, Wf + 3 * 65536, aoT, bo,
                         nullptr, out, nullptr, nullptr, bn_g, bn_b, bn_m, bn_v);
}

// ---------------------------------------------------------------------------
extern "C" void kernel_launch(void* const* d_in, const int* in_sizes, int n_in,
                              void* d_out, int out_size, void* d_ws, size_t ws_size,
                              hipStream_t stream)
{
    const float* x        = (const float*)d_in[0];
    const float* wq       = (const float*)d_in[1];
    const float* bq       = (const float*)d_in[2];
    const float* off_dw_w = (const float*)d_in[3];
    const float* off_dw_b = (const float*)d_in[4];
    const float* ln_g     = (const float*)d_in[5];
    const float* ln_b     = (const float*)d_in[6];
    const float* off_pw_w = (const float*)d_in[7];
    const float* wk       = (const float*)d_in[8];
    const float* bk       = (const float*)d_in[9];
    const float* wv       = (const float*)d_in[10];
    const float* bv       = (const float*)d_in[11];
    const float* wo       = (const float*)d_in[12];
    const float* bo       = (const float*)d_in[13];
    const float* bn_g     = (const float*)d_in[14];
    const float* bn_b     = (const float*)d_in[15];
    const float* bn_m     = (const float*)d_in[16];
    const float* bn_v     = (const float*)d_in[17];

    float* ws  = (float*)d_ws;
    float* q   = ws;                        // 4194304 f (fp32 for dwconv)
    float* off = q + 4194304;               // 1048576 f
    unsigned short* us  = (unsigned short*)(off + 1048576);
    unsigned short* Wf  = us;               //  262144 us (4 frag-packed weights)
    unsigned short* xT  = Wf  + 262144;     // 4194304 us
    unsigned short* qT  = xT  + 4194304;    // 4194304 us
    unsigned short* xsT = qT  + 4194304;    // 1048576 us
    unsigned short* kT  = xsT + 1048576;    // 1048576 us
    unsigned short* vbf = kT  + 1048576;    // 1048576 us
    unsigned short* aoT = vbf + 1048576;    // 4194304 us
    float* out = (float*)d_out;

    int maxb = 0;
    hipOccupancyMaxActiveBlocksPerMultiprocessor(&maxb, fused_k, 256, 0);
    if (maxb < 1) maxb = 1;
    long long grid = (long long)maxb * 256;
    if (grid > 1024) grid = 1024;

    void* kargs[] = {
        (void*)&x, (void*)&wq, (void*)&bq, (void*)&off_dw_w, (void*)&off_dw_b,
        (void*)&ln_g, (void*)&ln_b, (void*)&off_pw_w,
        (void*)&wk, (void*)&bk, (void*)&wv, (void*)&bv,
        (void*)&wo, (void*)&bo,
        (void*)&bn_g, (void*)&bn_b, (void*)&bn_m, (void*)&bn_v,
        (void*)&q, (void*)&off, (void*)&Wf, (void*)&xT,
        (void*)&qT, (void*)&xsT, (void*)&kT, (void*)&vbf, (void*)&aoT, (void*)&out
    };
    hipLaunchCooperativeKernel((const void*)fused_k, dim3((unsigned)grid), dim3(256),
                               kargs, 0, stream);
}

// Round 12
// 149.971 us; speedup vs baseline: 2.5862x; 2.5862x over previous
//
#include <hip/hip_runtime.h>
#include <hip/hip_bf16.h>
#include <math.h>

#define BATCH 16
#define CH    256
#define HW    1024
#define NS    256
#define NH    16
#define DH    16

typedef __attribute__((ext_vector_type(8))) short short8v;
typedef __attribute__((ext_vector_type(4))) float float4v;

__device__ __forceinline__ unsigned short f2bf(float f) {
    return __builtin_bit_cast(unsigned short, __float2bfloat16(f));
}
__device__ __forceinline__ unsigned pack2(float lo, float hi) {
    return (unsigned)f2bf(lo) | ((unsigned)f2bf(hi) << 16);
}

// ---------------------------------------------------------------------------
// prep: blocks 0..1023   -> weight repack (4 matrices, A-frag order)
//       blocks 1024..1279 -> x[b][c][p] fp32 -> xT[b][p][c] bf16
// Wf[mat][((ot*8+kt)*64+l)*8+i] = W[ot*16+(l&15)][kt*32+8*(l>>4)+i]
// ---------------------------------------------------------------------------
__global__ __launch_bounds__(256) void prep_k(
    const float* __restrict__ wq, const float* __restrict__ wk,
    const float* __restrict__ wv, const float* __restrict__ wo,
    unsigned short* __restrict__ Wf,
    const float* __restrict__ x, unsigned short* __restrict__ xT)
{
    int blk = blockIdx.x;
    if (blk < 1024) {
        const float* W;
        switch (blk >> 8) {
            case 0: W = wq; break;
            case 1: W = wk; break;
            case 2: W = wv; break;
            default: W = wo; break;
        }
        int e = (blk & 255) * 256 + threadIdx.x;     // 0..65535
        int i = e & 7, l = (e >> 3) & 63, kt = (e >> 9) & 7, ot = e >> 12;
        float v = W[(ot * 16 + (l & 15)) * 256 + kt * 32 + 8 * (l >> 4) + i];
        Wf[(blk >> 8) * 65536 + e] = f2bf(v);
    } else {
        int xb = blk - 1024;                          // 0..255
        int b = xb >> 4, pblk = (xb >> 2) & 3, cblk = xb & 3;
        int p = pblk * 256 + threadIdx.x;
        const float* xp = x + (size_t)b * CH * HW + p;
        unsigned short* o = xT + ((size_t)b * HW + p) * CH;
        #pragma unroll
        for (int cc = 0; cc < 64; cc += 8) {
            int c0 = cblk * 64 + cc;
            short8v t;
            #pragma unroll
            for (int i = 0; i < 8; ++i) t[i] = (short)f2bf(xp[(size_t)(c0 + i) * HW]);
            *(short8v*)&o[c0] = t;
        }
    }
}

// ---------------------------------------------------------------------------
// bf16 MFMA GEMM conv1x1 (packed Wf): C[o][p] = W[o][:] . X[:][p]  (K=256)
// MODE 0: Q  -> outF fp32 [b][o][p] + outB bf16 qT [b][p][o] (pre-scaled 0.25)
// MODE 2: O  -> outF fp32 d_out with BN epilogue
// ---------------------------------------------------------------------------
template<int P, int MODE>
__global__ __launch_bounds__(256) void gemm_k(
    const unsigned short* __restrict__ Wf, const unsigned short* __restrict__ XT,
    const float* __restrict__ bias,
    float* __restrict__ outF, unsigned short* __restrict__ outB,
    const float* __restrict__ bn_g, const float* __restrict__ bn_b,
    const float* __restrict__ bn_m, const float* __restrict__ bn_v)
{
    const int b = blockIdx.z;

    const int t = threadIdx.x, lane = t & 63, wvi = t >> 6;
    const int g = lane >> 4, col = lane & 15;
    const int o0 = blockIdx.x * 64;
    const int p0 = blockIdx.y * 128 + wvi * 32;
    const unsigned short* xb = XT + ((size_t)b * P + p0) * CH;

    float4v acc[4][2];
    #pragma unroll
    for (int mi = 0; mi < 4; ++mi)
        #pragma unroll
        for (int ni = 0; ni < 2; ++ni) {
            float4v z = {0.f, 0.f, 0.f, 0.f};
            acc[mi][ni] = z;
        }

    #pragma unroll
    for (int kt = 0; kt < 8; ++kt) {
        short8v af[4], bf[2];
        #pragma unroll
        for (int mi = 0; mi < 4; ++mi)
            af[mi] = *(const short8v*)&Wf[(((((o0 >> 4) + mi) * 8) + kt) * 64 + lane) * 8];
        #pragma unroll
        for (int ni = 0; ni < 2; ++ni)
            bf[ni] = *(const short8v*)&xb[(size_t)(ni * 16 + col) * CH + kt * 32 + 8 * g];
        #pragma unroll
        for (int mi = 0; mi < 4; ++mi)
            #pragma unroll
            for (int ni = 0; ni < 2; ++ni)
                acc[mi][ni] = __builtin_amdgcn_mfma_f32_16x16x32_bf16(
                    af[mi], bf[ni], acc[mi][ni], 0, 0, 0);
    }

    #pragma unroll
    for (int mi = 0; mi < 4; ++mi) {
        const int ob = o0 + mi * 16 + 4 * g;
        float bs[4];
        #pragma unroll
        for (int ii = 0; ii < 4; ++ii) bs[ii] = bias[ob + ii];

        if (MODE == 2) {
            float sc[4], sh[4];
            #pragma unroll
            for (int ii = 0; ii < 4; ++ii) {
                int o = ob + ii;
                float s = bn_g[o] * rsqrtf(bn_v[o] + 1e-5f);
                sc[ii] = s;
                sh[ii] = bn_b[o] - bn_m[o] * s + bs[ii] * s;
            }
            #pragma unroll
            for (int ni = 0; ni < 2; ++ni) {
                int p = p0 + ni * 16 + col;
                #pragma unroll
                for (int ii = 0; ii < 4; ++ii)
                    outF[((size_t)(b * CH + ob + ii)) * P + p] =
                        acc[mi][ni][ii] * sc[ii] + sh[ii];
            }
        } else {
            #pragma unroll
            for (int ni = 0; ni < 2; ++ni) {
                int p = p0 + ni * 16 + col;
                float v0 = acc[mi][ni][0] + bs[0];
                float v1 = acc[mi][ni][1] + bs[1];
                float v2 = acc[mi][ni][2] + bs[2];
                float v3 = acc[mi][ni][3] + bs[3];
                outF[((size_t)(b * CH + ob + 0)) * P + p] = v0;
                outF[((size_t)(b * CH + ob + 1)) * P + p] = v1;
                outF[((size_t)(b * CH + ob + 2)) * P + p] = v2;
                outF[((size_t)(b * CH + ob + 3)) * P + p] = v3;
                uint2 w;   // qT pre-scaled by 0.25 (exact pow2)
                w.x = pack2(v0 * 0.25f, v1 * 0.25f);
                w.y = pack2(v2 * 0.25f, v3 * 0.25f);
                *(uint2*)&outB[((size_t)(b * P + p)) * CH + ob] = w;
            }
        }
    }
}

// ---------------------------------------------------------------------------
// depthwise 9x9 conv, stride 2, pad 4 (q fp32 [b][c][32][32] -> off [b][c][16][16])
// ---------------------------------------------------------------------------
__global__ __launch_bounds__(256) void dwconv_k(
    const float* __restrict__ q, const float* __restrict__ w,
    const float* __restrict__ bias, float* __restrict__ off)
{
    int bc = blockIdx.x;
    int c  = bc & (CH - 1);
    __shared__ float plane[HW];
    __shared__ float kw[81];
    int t = threadIdx.x;
    const float* qp = q + (size_t)bc * HW;
    #pragma unroll
    for (int j = t; j < HW; j += 256) plane[j] = qp[j];
    if (t < 81) kw[t] = w[c * 81 + t];
    __syncthreads();
    int hk = t >> 4, wk = t & 15;
    float s = bias[c];
    int yb = hk * 2 - 4, xb = wk * 2 - 4;
    #pragma unroll
    for (int dy = 0; dy < 9; ++dy) {
        int yy = yb + dy;
        if ((unsigned)yy < 32u) {
            #pragma unroll
            for (int dx = 0; dx < 9; ++dx) {
                int xx = xb + dx;
                if ((unsigned)xx < 32u) s += kw[dy * 9 + dx] * plane[yy * 32 + xx];
            }
        }
    }
    off[(size_t)bc * NS + t] = s;
}

// ---------------------------------------------------------------------------
// fused: LN(channel) + GELU + projection + ref + tanh + bilinear grid sample
// -> xsT bf16 [b][s][c]
// ---------------------------------------------------------------------------
__device__ inline void block_reduce2(float& a, float& b, int t, float* sbuf)
{
    #pragma unroll
    for (int o = 32; o > 0; o >>= 1) {
        a += __shfl_down(a, o);
        b += __shfl_down(b, o);
    }
    int w = t >> 6;
    if ((t & 63) == 0) { sbuf[w * 2] = a; sbuf[w * 2 + 1] = b; }
    __syncthreads();
    a = sbuf[0] + sbuf[2] + sbuf[4] + sbuf[6];
    b = sbuf[1] + sbuf[3] + sbuf[5] + sbuf[7];
    __syncthreads();
}

__global__ __launch_bounds__(256) void lngs_k(
    const float* __restrict__ off, const float* __restrict__ ln_g,
    const float* __restrict__ ln_b, const float* __restrict__ pw,
    const float* __restrict__ x, unsigned short* __restrict__ xsT)
{
    __shared__ float sbuf[8];
    int bs = blockIdx.x;
    int b = bs >> 8, s = bs & 255;
    int c = threadIdx.x;
    float v = off[((size_t)(b * CH + c)) * NS + s];
    float a = v, q2 = v * v;
    block_reduce2(a, q2, c, sbuf);
    float mean = a * (1.0f / 256.0f);
    float var  = q2 * (1.0f / 256.0f) - mean * mean;
    float xn = (v - mean) * rsqrtf(var + 1e-5f) * ln_g[c] + ln_b[c];
    float g = 0.5f * xn * (1.0f + erff(xn * 0.70710678118654752f));
    float d0 = g * pw[c];
    float d1 = g * pw[CH + c];
    block_reduce2(d0, d1, c, sbuf);   // broadcasts sums to all threads

    int hk = s >> 4, wk = s & 15;
    float ry = ((hk + 0.5f) / 16.0f) * 2.0f - 1.0f;
    float rx = ((wk + 0.5f) / 16.0f) * 2.0f - 1.0f;
    float py = tanhf(d0 + ry);
    float px = tanhf(d1 + rx);

    float gx = (px + 1.0f) * 0.5f * 31.0f;
    float gy = (py + 1.0f) * 0.5f * 31.0f;
    float x0f = floorf(gx), y0f = floorf(gy);
    int ix = (int)x0f, iy = (int)y0f;
    float wx1 = gx - x0f, wx0 = 1.0f - wx1;
    float wy1 = gy - y0f, wy0 = 1.0f - wy1;
    const float* img = x + ((size_t)b * CH + c) * HW;
    float v00 = ((unsigned)iy < 32u && (unsigned)ix < 32u) ? img[iy * 32 + ix] : 0.0f;
    float v01 = ((unsigned)iy < 32u && (unsigned)(ix + 1) < 32u) ? img[iy * 32 + ix + 1] : 0.0f;
    float v10 = ((unsigned)(iy + 1) < 32u && (unsigned)ix < 32u) ? img[(iy + 1) * 32 + ix] : 0.0f;
    float v11 = ((unsigned)(iy + 1) < 32u && (unsigned)(ix + 1) < 32u) ? img[(iy + 1) * 32 + ix + 1] : 0.0f;
    float vv = wy0 * wx0 * v00 + wy0 * wx1 * v01 + wy1 * wx0 * v10 + wy1 * wx1 * v11;
    xsT[(size_t)bs * CH + c] = f2bf(vv);
}

// ---------------------------------------------------------------------------
// fused KV-build + MFMA attention. One 1024-thread block per (b,h).
// Each of the 16 waves builds ONE K n-tile and ONE V n-tile (bit-identical
// MFMA/bias/f2bf sequence to the former standalone KV GEMM; layouts verified
// on HW in R7), writing directly into the QK A-frag layout (compact, stride-0
// zero trick) and the PV A-frag layout (conflict-free, no swizzle). Then each
// wave runs softmax+PV over its own 64 query rows (R9 kernel body).
// ---------------------------------------------------------------------------
__global__ __launch_bounds__(1024) void attn_fused_k(
    const unsigned short* __restrict__ qT, const unsigned short* __restrict__ xsT,
    const unsigned short* __restrict__ Wf,
    const float* __restrict__ bk, const float* __restrict__ bv,
    unsigned short* __restrict__ aoT)
{
    const int bh = blockIdx.x;
    const int b = bh >> 4, h = bh & 15;

    __shared__ short Kp[16 * 32 * 8 + 8];   // 8KB + 16B zero slot (QK A-frag)
    __shared__ short Vp[8 * 64 * 8];        // 8KB PV A-frag (8 chunks of n=32)
    __shared__ short Ps[16][16 * 32];       // 16KB per-wave P scratch

    const int tid  = threadIdx.x;
    const int lane = tid & 63;
    const int wvi  = tid >> 6;      // 0..15
    const int col  = lane & 15;
    const int g    = lane >> 4;

    // ---- build K, V: wave wvi builds n-tile t = wvi ----
    {
        const unsigned short* WfK = Wf + 1 * 65536 + h * 4096;  // wk tiles, ot=h
        const unsigned short* WfV = Wf + 2 * 65536 + h * 4096;  // wv tiles, ot=h
        float bk4[4];
        #pragma unroll
        for (int j = 0; j < 4; ++j) bk4[j] = bk[h * 16 + 4 * g + j];
        const float bvv = bv[h * 16 + col];

        const int t  = wvi;
        const int n0 = t * 16;
        float4v accK = {0.f, 0.f, 0.f, 0.f};
        float4v accV = {0.f, 0.f, 0.f, 0.f};
        #pragma unroll
        for (int kt = 0; kt < 8; ++kt) {
            short8v xsf = *(const short8v*)&xsT[((size_t)(b * NS + n0 + col)) * CH + kt * 32 + 8 * g];
            short8v wkf = *(const short8v*)&WfK[(kt * 64 + lane) * 8];
            short8v wvf = *(const short8v*)&WfV[(kt * 64 + lane) * 8];
            accK = __builtin_amdgcn_mfma_f32_16x16x32_bf16(wkf, xsf, accK, 0, 0, 0);
            accV = __builtin_amdgcn_mfma_f32_16x16x32_bf16(xsf, wvf, accV, 0, 0, 0);
        }
        uint2 wrk;
        wrk.x = pack2(accK[0] + bk4[0], accK[1] + bk4[1]);
        wrk.y = pack2(accK[2] + bk4[2], accK[3] + bk4[3]);
        *(uint2*)&Kp[(t * 32 + (g >> 1) * 16 + col) * 8 + 4 * (g & 1)] = wrk;
        uint2 wrv;
        wrv.x = pack2(accV[0] + bvv, accV[1] + bvv);
        wrv.y = pack2(accV[2] + bvv, accV[3] + bvv);
        *(uint2*)&Vp[((t >> 1) * 64 + col + 16 * ((2 * t + (g >> 1)) & 3)) * 8 + 4 * (g & 1)] = wrv;
    }
    if (tid == 0) {
        short8v z = {0, 0, 0, 0, 0, 0, 0, 0};
        *(short8v*)&Kp[16 * 32 * 8] = z;
    }
    __syncthreads();

    const unsigned short* Qb = qT + (size_t)b * HW * CH + h * 16;
    unsigned short*       Ob = aoT + (size_t)b * HW * CH + h * 16;
    char* pbase = (char*)Ps[wvi];
    // stride-0 zero trick for the padded d=16..31 half of the QK A operand
    const char* kbase = (const char*)Kp + ((lane < 32) ? lane * 16 : 16 * 32 * 16);
    const int   kstep = (lane < 32) ? 512 : 0;

    for (int mt = 0; mt < 4; ++mt) {
        const int m0 = wvi * 64 + mt * 16;

        short8v qf = {0, 0, 0, 0, 0, 0, 0, 0};
        if (g < 2)
            qf = *(const short8v*)&Qb[(size_t)(m0 + col) * CH + 8 * g];

        float4v p[16];
        #pragma unroll
        for (int t = 0; t < 16; ++t) {
            short8v kf = *(const short8v*)(kbase + t * kstep);
            float4v z = {0.f, 0.f, 0.f, 0.f};
            p[t] = __builtin_amdgcn_mfma_f32_16x16x32_bf16(kf, qf, z, 0, 0, 0);
        }

        // tree max (bit-exact reassociation of fmax)
        float mx4[16];
        #pragma unroll
        for (int t = 0; t < 16; ++t)
            mx4[t] = fmaxf(fmaxf(p[t][0], p[t][1]), fmaxf(p[t][2], p[t][3]));
        #pragma unroll
        for (int o = 8; o >= 1; o >>= 1)
            #pragma unroll
            for (int i = 0; i < 8; ++i)
                if (i < o) mx4[i] = fmaxf(mx4[i], mx4[i + o]);
        float mx = mx4[0];
        mx = fmaxf(mx, __shfl_xor(mx, 16));
        mx = fmaxf(mx, __shfl_xor(mx, 32));

        float s4[4] = {0.f, 0.f, 0.f, 0.f};
        #pragma unroll
        for (int t = 0; t < 16; ++t) {
            #pragma unroll
            for (int i = 0; i < 4; ++i) {
                float e = __expf(p[t][i] - mx);   // 0.25 pre-folded into qT
                p[t][i] = e;
                s4[i] += e;
            }
        }
        float sum = (s4[0] + s4[1]) + (s4[2] + s4[3]);
        sum += __shfl_xor(sum, 16);
        sum += __shfl_xor(sum, 32);
        const float inv = 1.0f / sum;

        float4v acc = {0.f, 0.f, 0.f, 0.f};
        #pragma unroll
        for (int c = 0; c < 8; ++c) {
            #pragma unroll
            for (int pp = 0; pp < 2; ++pp) {
                float4v pv = p[2 * c + pp];
                uint2 wr;
                wr.x = pack2(pv[0], pv[1]);
                wr.y = pack2(pv[2], pv[3]);
                *(uint2*)(pbase + ((col * 64 + (16 * pp + 4 * g) * 2) ^ ((col & 7) << 4))) = wr;
            }
            short8v pf = *(const short8v*)(pbase + ((col * 64 + 16 * g) ^ ((col & 7) << 4)));
            short8v vf = *(const short8v*)&Vp[(c * 64 + lane) * 8];
            acc = __builtin_amdgcn_mfma_f32_16x16x32_bf16(vf, pf, acc, 0, 0, 0);
        }

        uint2 w;
        w.x = pack2(acc[0] * inv, acc[1] * inv);
        w.y = pack2(acc[2] * inv, acc[3] * inv);
        *(uint2*)&Ob[(size_t)(m0 + col) * CH + 4 * g] = w;
    }
}

// ---------------------------------------------------------------------------
extern "C" void kernel_launch(void* const* d_in, const int* in_sizes, int n_in,
                              void* d_out, int out_size, void* d_ws, size_t ws_size,
                              hipStream_t stream)
{
    const float* x        = (const float*)d_in[0];
    const float* wq       = (const float*)d_in[1];
    const float* bq       = (const float*)d_in[2];
    const float* off_dw_w = (const float*)d_in[3];
    const float* off_dw_b = (const float*)d_in[4];
    const float* ln_g     = (const float*)d_in[5];
    const float* ln_b     = (const float*)d_in[6];
    const float* off_pw_w = (const float*)d_in[7];
    const float* wk       = (const float*)d_in[8];
    const float* bk       = (const float*)d_in[9];
    const float* wv       = (const float*)d_in[10];
    const float* bv       = (const float*)d_in[11];
    const float* wo       = (const float*)d_in[12];
    const float* bo       = (const float*)d_in[13];
    const float* bn_g     = (const float*)d_in[14];
    const float* bn_b     = (const float*)d_in[15];
    const float* bn_m     = (const float*)d_in[16];
    const float* bn_v     = (const float*)d_in[17];

    float* ws  = (float*)d_ws;
    float* q   = ws;                        // 4194304 f (fp32 for dwconv)
    float* off = q + 4194304;               // 1048576 f
    unsigned short* us  = (unsigned short*)(off + 1048576);
    unsigned short* Wf  = us;               //  262144 us (4 frag-packed weights)
    unsigned short* xT  = Wf  + 262144;     // 4194304 us
    unsigned short* qT  = xT  + 4194304;    // 4194304 us
    unsigned short* xsT = qT  + 4194304;    // 1048576 us
    unsigned short* aoT = xsT + 1048576;    // 4194304 us

    prep_k<<<1280, 256, 0, stream>>>(wq, wk, wv, wo, Wf, x, xT);
    gemm_k<HW, 0><<<dim3(4, 8, BATCH), 256, 0, stream>>>(
        Wf, xT, bq, q, qT, nullptr, nullptr, nullptr, nullptr);
    dwconv_k<<<BATCH * CH, 256, 0, stream>>>(q, off_dw_w, off_dw_b, off);
    lngs_k<<<BATCH * NS, 256, 0, stream>>>(off, ln_g, ln_b, off_pw_w, x, xsT);
    attn_fused_k<<<BATCH * NH, 1024, 0, stream>>>(qT, xsT, Wf, bk, bv, aoT);
    gemm_k<HW, 2><<<dim3(4, 8, BATCH), 256, 0, stream>>>(
        Wf + 3 * 65536, aoT, bo, (float*)d_out, nullptr,
        bn_g, bn_b, bn_m, bn_v);
}

// Round 13
// 111.746 us; speedup vs baseline: 3.4708x; 1.3421x over previous
//
#include <hip/hip_runtime.h>
#include <hip/hip_bf16.h>
#include <math.h>

#define BATCH 16
#define CH    256
#define HW    1024
#define NS    256
#define NH    16
#define DH    16

typedef __attribute__((ext_vector_type(8))) short short8v;
typedef __attribute__((ext_vector_type(4))) float float4v;

__device__ __forceinline__ unsigned short f2bf(float f) {
    return __builtin_bit_cast(unsigned short, __float2bfloat16(f));
}
__device__ __forceinline__ unsigned pack2(float lo, float hi) {
    return (unsigned)f2bf(lo) | ((unsigned)f2bf(hi) << 16);
}

// ---------------------------------------------------------------------------
// prep: blocks 0..1023   -> weight repack (4 matrices, A-frag order)
//       blocks 1024..1279 -> x[b][c][p] fp32 -> xT[b][p][c] bf16
// Wf[mat][((ot*8+kt)*64+l)*8+i] = W[ot*16+(l&15)][kt*32+8*(l>>4)+i]
// ---------------------------------------------------------------------------
__global__ __launch_bounds__(256) void prep_k(
    const float* __restrict__ wq, const float* __restrict__ wk,
    const float* __restrict__ wv, const float* __restrict__ wo,
    unsigned short* __restrict__ Wf,
    const float* __restrict__ x, unsigned short* __restrict__ xT)
{
    int blk = blockIdx.x;
    if (blk < 1024) {
        const float* W;
        switch (blk >> 8) {
            case 0: W = wq; break;
            case 1: W = wk; break;
            case 2: W = wv; break;
            default: W = wo; break;
        }
        int e = (blk & 255) * 256 + threadIdx.x;     // 0..65535
        int i = e & 7, l = (e >> 3) & 63, kt = (e >> 9) & 7, ot = e >> 12;
        float v = W[(ot * 16 + (l & 15)) * 256 + kt * 32 + 8 * (l >> 4) + i];
        Wf[(blk >> 8) * 65536 + e] = f2bf(v);
    } else {
        int xb = blk - 1024;                          // 0..255
        int b = xb >> 4, pblk = (xb >> 2) & 3, cblk = xb & 3;
        int p = pblk * 256 + threadIdx.x;
        const float* xp = x + (size_t)b * CH * HW + p;
        unsigned short* o = xT + ((size_t)b * HW + p) * CH;
        #pragma unroll
        for (int cc = 0; cc < 64; cc += 8) {
            int c0 = cblk * 64 + cc;
            short8v t;
            #pragma unroll
            for (int i = 0; i < 8; ++i) t[i] = (short)f2bf(xp[(size_t)(c0 + i) * HW]);
            *(short8v*)&o[c0] = t;
        }
    }
}

// ---------------------------------------------------------------------------
// bf16 MFMA GEMM conv1x1 (packed Wf): C[o][p] = W[o][:] . X[:][p]  (K=256)
// MODE 0: Q  -> outF fp32 [b][o][p] + outB bf16 qH [b][h][p][16] (pre-scaled 0.25)
// MODE 1: KV -> mat 0: kH bf16 [b][h][n][16]; mat 1: v bf16 [b][c][n]
// MODE 2: O  -> outF fp32 d_out with BN epilogue; XT is aoH [b][h][m][16]
// ---------------------------------------------------------------------------
template<int P, int MODE>
__global__ __launch_bounds__(256) void gemm_k(
    const unsigned short* __restrict__ Wf, const unsigned short* __restrict__ XT,
    const float* __restrict__ bias, const float* __restrict__ bias2,
    float* __restrict__ outF, unsigned short* __restrict__ outB,
    unsigned short* __restrict__ outB2,
    const float* __restrict__ bn_g, const float* __restrict__ bn_b,
    const float* __restrict__ bn_m, const float* __restrict__ bn_v)
{
    const int bz  = blockIdx.z;
    const int b   = (MODE == 1) ? (bz & 15) : bz;
    const int mat = (MODE == 1) ? (bz >> 4) : 0;
    const unsigned short* Wfm = Wf + mat * 65536;

    const int t = threadIdx.x, lane = t & 63, wvi = t >> 6;
    const int g = lane >> 4, col = lane & 15;
    const int o0 = blockIdx.x * 64;
    const int p0 = blockIdx.y * 128 + wvi * 32;
    const unsigned short* xb = XT + ((size_t)b * P + p0) * CH;   // MODE 0/1

    float4v acc[4][2];
    #pragma unroll
    for (int mi = 0; mi < 4; ++mi)
        #pragma unroll
        for (int ni = 0; ni < 2; ++ni) {
            float4v z = {0.f, 0.f, 0.f, 0.f};
            acc[mi][ni] = z;
        }

    #pragma unroll
    for (int kt = 0; kt < 8; ++kt) {
        short8v af[4], bf[2];
        #pragma unroll
        for (int mi = 0; mi < 4; ++mi)
            af[mi] = *(const short8v*)&Wfm[(((((o0 >> 4) + mi) * 8) + kt) * 64 + lane) * 8];
        #pragma unroll
        for (int ni = 0; ni < 2; ++ni) {
            if (MODE == 2) {
                // aoH head-major: channels kt*32+8g..+7 lie inside head hh
                const int hh = kt * 2 + (g >> 1);
                const int p  = p0 + ni * 16 + col;
                bf[ni] = *(const short8v*)&XT[(((size_t)(b * 16 + hh) * P + p) << 4) + 8 * (g & 1)];
            } else {
                bf[ni] = *(const short8v*)&xb[(size_t)(ni * 16 + col) * CH + kt * 32 + 8 * g];
            }
        }
        #pragma unroll
        for (int mi = 0; mi < 4; ++mi)
            #pragma unroll
            for (int ni = 0; ni < 2; ++ni)
                acc[mi][ni] = __builtin_amdgcn_mfma_f32_16x16x32_bf16(
                    af[mi], bf[ni], acc[mi][ni], 0, 0, 0);
    }

    const float* bp = (MODE == 1 && mat == 1) ? bias2 : bias;
    #pragma unroll
    for (int mi = 0; mi < 4; ++mi) {
        const int ob = o0 + mi * 16 + 4 * g;
        float bs[4];
        #pragma unroll
        for (int ii = 0; ii < 4; ++ii) bs[ii] = bp[ob + ii];

        if (MODE == 2) {
            float sc[4], sh[4];
            #pragma unroll
            for (int ii = 0; ii < 4; ++ii) {
                int o = ob + ii;
                float s = bn_g[o] * rsqrtf(bn_v[o] + 1e-5f);
                sc[ii] = s;
                sh[ii] = bn_b[o] - bn_m[o] * s + bs[ii] * s;
            }
            #pragma unroll
            for (int ni = 0; ni < 2; ++ni) {
                int p = p0 + ni * 16 + col;
                #pragma unroll
                for (int ii = 0; ii < 4; ++ii)
                    outF[((size_t)(b * CH + ob + ii)) * P + p] =
                        acc[mi][ni][ii] * sc[ii] + sh[ii];
            }
        } else {
            const int hh = (o0 >> 4) + mi;     // ob>>4 (4g < 16)
            #pragma unroll
            for (int ni = 0; ni < 2; ++ni) {
                int p = p0 + ni * 16 + col;
                float v0 = acc[mi][ni][0] + bs[0];
                float v1 = acc[mi][ni][1] + bs[1];
                float v2 = acc[mi][ni][2] + bs[2];
                float v3 = acc[mi][ni][3] + bs[3];
                if (MODE == 0) {
                    outF[((size_t)(b * CH + ob + 0)) * P + p] = v0;
                    outF[((size_t)(b * CH + ob + 1)) * P + p] = v1;
                    outF[((size_t)(b * CH + ob + 2)) * P + p] = v2;
                    outF[((size_t)(b * CH + ob + 3)) * P + p] = v3;
                    uint2 w;   // qH pre-scaled by 0.25 (exact pow2)
                    w.x = pack2(v0 * 0.25f, v1 * 0.25f);
                    w.y = pack2(v2 * 0.25f, v3 * 0.25f);
                    *(uint2*)&outB[(((size_t)(b * 16 + hh) * P + p) << 4) + 4 * g] = w;
                } else { // MODE 1
                    if (mat == 0) {
                        uint2 w;
                        w.x = pack2(v0, v1);
                        w.y = pack2(v2, v3);
                        *(uint2*)&outB[(((size_t)(b * 16 + hh) * P + p) << 4) + 4 * g] = w;
                    } else {
                        outB2[((size_t)(b * CH + ob + 0)) * P + p] = f2bf(v0);
                        outB2[((size_t)(b * CH + ob + 1)) * P + p] = f2bf(v1);
                        outB2[((size_t)(b * CH + ob + 2)) * P + p] = f2bf(v2);
                        outB2[((size_t)(b * CH + ob + 3)) * P + p] = f2bf(v3);
                    }
                }
            }
        }
    }
}

// ---------------------------------------------------------------------------
// depthwise 9x9 conv, stride 2, pad 4 (q fp32 [b][c][32][32] -> off [b][c][16][16])
// ---------------------------------------------------------------------------
__global__ __launch_bounds__(256) void dwconv_k(
    const float* __restrict__ q, const float* __restrict__ w,
    const float* __restrict__ bias, float* __restrict__ off)
{
    int bc = blockIdx.x;
    int c  = bc & (CH - 1);
    __shared__ float plane[HW];
    __shared__ float kw[81];
    int t = threadIdx.x;
    const float* qp = q + (size_t)bc * HW;
    #pragma unroll
    for (int j = t; j < HW; j += 256) plane[j] = qp[j];
    if (t < 81) kw[t] = w[c * 81 + t];
    __syncthreads();
    int hk = t >> 4, wk = t & 15;
    float s = bias[c];
    int yb = hk * 2 - 4, xb = wk * 2 - 4;
    #pragma unroll
    for (int dy = 0; dy < 9; ++dy) {
        int yy = yb + dy;
        if ((unsigned)yy < 32u) {
            #pragma unroll
            for (int dx = 0; dx < 9; ++dx) {
                int xx = xb + dx;
                if ((unsigned)xx < 32u) s += kw[dy * 9 + dx] * plane[yy * 32 + xx];
            }
        }
    }
    off[(size_t)bc * NS + t] = s;
}

// ---------------------------------------------------------------------------
// fused: LN(channel) + GELU + projection + ref + tanh + bilinear grid sample
// -> xsT bf16 [b][s][c]
// ---------------------------------------------------------------------------
__device__ inline void block_reduce2(float& a, float& b, int t, float* sbuf)
{
    #pragma unroll
    for (int o = 32; o > 0; o >>= 1) {
        a += __shfl_down(a, o);
        b += __shfl_down(b, o);
    }
    int w = t >> 6;
    if ((t & 63) == 0) { sbuf[w * 2] = a; sbuf[w * 2 + 1] = b; }
    __syncthreads();
    a = sbuf[0] + sbuf[2] + sbuf[4] + sbuf[6];
    b = sbuf[1] + sbuf[3] + sbuf[5] + sbuf[7];
    __syncthreads();
}

__global__ __launch_bounds__(256) void lngs_k(
    const float* __restrict__ off, const float* __restrict__ ln_g,
    const float* __restrict__ ln_b, const float* __restrict__ pw,
    const float* __restrict__ x, unsigned short* __restrict__ xsT)
{
    __shared__ float sbuf[8];
    int bs = blockIdx.x;
    int b = bs >> 8, s = bs & 255;
    int c = threadIdx.x;
    float v = off[((size_t)(b * CH + c)) * NS + s];
    float a = v, q2 = v * v;
    block_reduce2(a, q2, c, sbuf);
    float mean = a * (1.0f / 256.0f);
    float var  = q2 * (1.0f / 256.0f) - mean * mean;
    float xn = (v - mean) * rsqrtf(var + 1e-5f) * ln_g[c] + ln_b[c];
    float g = 0.5f * xn * (1.0f + erff(xn * 0.70710678118654752f));
    float d0 = g * pw[c];
    float d1 = g * pw[CH + c];
    block_reduce2(d0, d1, c, sbuf);   // broadcasts sums to all threads

    int hk = s >> 4, wk = s & 15;
    float ry = ((hk + 0.5f) / 16.0f) * 2.0f - 1.0f;
    float rx = ((wk + 0.5f) / 16.0f) * 2.0f - 1.0f;
    float py = tanhf(d0 + ry);
    float px = tanhf(d1 + rx);

    float gx = (px + 1.0f) * 0.5f * 31.0f;
    float gy = (py + 1.0f) * 0.5f * 31.0f;
    float x0f = floorf(gx), y0f = floorf(gy);
    int ix = (int)x0f, iy = (int)y0f;
    float wx1 = gx - x0f, wx0 = 1.0f - wx1;
    float wy1 = gy - y0f, wy0 = 1.0f - wy1;
    const float* img = x + ((size_t)b * CH + c) * HW;
    float v00 = ((unsigned)iy < 32u && (unsigned)ix < 32u) ? img[iy * 32 + ix] : 0.0f;
    float v01 = ((unsigned)iy < 32u && (unsigned)(ix + 1) < 32u) ? img[iy * 32 + ix + 1] : 0.0f;
    float v10 = ((unsigned)(iy + 1) < 32u && (unsigned)ix < 32u) ? img[(iy + 1) * 32 + ix] : 0.0f;
    float v11 = ((unsigned)(iy + 1) < 32u && (unsigned)(ix + 1) < 32u) ? img[(iy + 1) * 32 + ix + 1] : 0.0f;
    float vv = wy0 * wx0 * v00 + wy0 * wx1 * v01 + wy1 * wx0 * v10 + wy1 * wx1 * v11;
    xsT[(size_t)bs * CH + c] = f2bf(vv);
}

// ---------------------------------------------------------------------------
// MFMA attention (R9 body, head-major layouts).
// qH[b][h][m][16] (pre-scaled 0.25), kH[b][h][n][16], v[b][c][n] -> aoH[b][h][m][16]
// Kp compact + stride-0 zero trick; softmax tree-max/4-acc; LDS P round-trip.
// ---------------------------------------------------------------------------
__global__ __launch_bounds__(256) void attn_mfma_k(
    const unsigned short* __restrict__ qH, const unsigned short* __restrict__ kH,
    const unsigned short* __restrict__ vbf, unsigned short* __restrict__ aoH)
{
    const int bh   = blockIdx.x >> 2;
    const int mseg = blockIdx.x & 3;
    const int b = bh >> 4, h = bh & 15;

    __shared__ short Kp[16 * 32 * 8 + 8];  // 8KB + 16B zero slot
    __shared__ short Vsh[16 * 256];        // [d][n], byte ^= (d&7)<<4
    __shared__ short Ps[4][16 * 32];       // per-wave P scratch, byte ^= (m&7)<<4

    const int tid  = threadIdx.x;
    const int lane = tid & 63;
    const int wvi  = tid >> 6;
    const int col  = lane & 15;
    const int g    = lane >> 4;

    const unsigned short* kHb = kH + ((size_t)(b * 16 + h) * NS << 4);
    for (int e = tid; e < 512; e += 256) {
        int t = e >> 5, l = e & 31, gg = l >> 4, c = l & 15;
        short8v kk = *(const short8v*)&kHb[((16 * t + c) << 4) + 8 * gg];
        *(short8v*)&Kp[(t * 32 + l) * 8] = kk;
    }
    if (tid == 0) {
        short8v z = {0, 0, 0, 0, 0, 0, 0, 0};
        *(short8v*)&Kp[16 * 32 * 8] = z;
    }
    {
        const unsigned short* Vb = vbf + ((size_t)(b * CH + h * 16)) * NS;
        int d = tid >> 4, n0 = (tid & 15) * 16;
        char* vb = (char*)Vsh;
        #pragma unroll
        for (int hh = 0; hh < 2; ++hh) {
            short8v pk = *(const short8v*)&Vb[(size_t)d * NS + n0 + 8 * hh];
            *(short8v*)(vb + ((d * 512 + (n0 + 8 * hh) * 2) ^ ((d & 7) << 4))) = pk;
        }
    }
    __syncthreads();

    const unsigned short* Qb = qH + ((size_t)(b * 16 + h) * HW << 4);
    unsigned short*       Ob = aoH + ((size_t)(b * 16 + h) * HW << 4);
    char* pbase = (char*)Ps[wvi];
    // stride-0 zero trick for the padded d=16..31 half of the QK A operand
    const char* kbase = (const char*)Kp + ((lane < 32) ? lane * 16 : 16 * 32 * 16);
    const int   kstep = (lane < 32) ? 512 : 0;

    for (int mt = 0; mt < 4; ++mt) {
        const int m0 = mseg * 256 + wvi * 64 + mt * 16;

        short8v qf = {0, 0, 0, 0, 0, 0, 0, 0};
        if (g < 2)
            qf = *(const short8v*)&Qb[((m0 + col) << 4) + 8 * g];

        float4v p[16];
        #pragma unroll
        for (int t = 0; t < 16; ++t) {
            short8v kf = *(const short8v*)(kbase + t * kstep);
            float4v z = {0.f, 0.f, 0.f, 0.f};
            p[t] = __builtin_amdgcn_mfma_f32_16x16x32_bf16(kf, qf, z, 0, 0, 0);
        }

        // tree max (bit-exact reassociation of fmax)
        float mx4[16];
        #pragma unroll
        for (int t = 0; t < 16; ++t)
            mx4[t] = fmaxf(fmaxf(p[t][0], p[t][1]), fmaxf(p[t][2], p[t][3]));
        #pragma unroll
        for (int o = 8; o >= 1; o >>= 1)
            #pragma unroll
            for (int i = 0; i < 8; ++i)
                if (i < o) mx4[i] = fmaxf(mx4[i], mx4[i + o]);
        float mx = mx4[0];
        mx = fmaxf(mx, __shfl_xor(mx, 16));
        mx = fmaxf(mx, __shfl_xor(mx, 32));

        float s4[4] = {0.f, 0.f, 0.f, 0.f};
        #pragma unroll
        for (int t = 0; t < 16; ++t) {
            #pragma unroll
            for (int i = 0; i < 4; ++i) {
                float e = __expf(p[t][i] - mx);   // 0.25 pre-folded into qH
                p[t][i] = e;
                s4[i] += e;
            }
        }
        float sum = (s4[0] + s4[1]) + (s4[2] + s4[3]);
        sum += __shfl_xor(sum, 16);
        sum += __shfl_xor(sum, 32);
        const float inv = 1.0f / sum;

        float4v acc = {0.f, 0.f, 0.f, 0.f};
        #pragma unroll
        for (int c = 0; c < 8; ++c) {
            #pragma unroll
            for (int pp = 0; pp < 2; ++pp) {
                float4v pv = p[2 * c + pp];
                uint2 wr;
                wr.x = pack2(pv[0], pv[1]);
                wr.y = pack2(pv[2], pv[3]);
                *(uint2*)(pbase + ((col * 64 + (16 * pp + 4 * g) * 2) ^ ((col & 7) << 4))) = wr;
            }
            short8v pf = *(const short8v*)(pbase + ((col * 64 + 16 * g) ^ ((col & 7) << 4)));
            short8v vf = *(const short8v*)((char*)Vsh + ((col * 512 + 64 * c + 16 * g) ^ ((col & 7) << 4)));
            acc = __builtin_amdgcn_mfma_f32_16x16x32_bf16(vf, pf, acc, 0, 0, 0);
        }

        uint2 w;
        w.x = pack2(acc[0] * inv, acc[1] * inv);
        w.y = pack2(acc[2] * inv, acc[3] * inv);
        *(uint2*)&Ob[((m0 + col) << 4) + 4 * g] = w;
    }
}

// ---------------------------------------------------------------------------
extern "C" void kernel_launch(void* const* d_in, const int* in_sizes, int n_in,
                              void* d_out, int out_size, void* d_ws, size_t ws_size,
                              hipStream_t stream)
{
    const float* x        = (const float*)d_in[0];
    const float* wq       = (const float*)d_in[1];
    const float* bq       = (const float*)d_in[2];
    const float* off_dw_w = (const float*)d_in[3];
    const float* off_dw_b = (const float*)d_in[4];
    const float* ln_g     = (const float*)d_in[5];
    const float* ln_b     = (const float*)d_in[6];
    const float* off_pw_w = (const float*)d_in[7];
    const float* wk       = (const float*)d_in[8];
    const float* bk       = (const float*)d_in[9];
    const float* wv       = (const float*)d_in[10];
    const float* bv       = (const float*)d_in[11];
    const float* wo       = (const float*)d_in[12];
    const float* bo       = (const float*)d_in[13];
    const float* bn_g     = (const float*)d_in[14];
    const float* bn_b     = (const float*)d_in[15];
    const float* bn_m     = (const float*)d_in[16];
    const float* bn_v     = (const float*)d_in[17];

    float* ws  = (float*)d_ws;
    float* q   = ws;                        // 4194304 f (fp32 for dwconv)
    float* off = q + 4194304;               // 1048576 f
    unsigned short* us  = (unsigned short*)(off + 1048576);
    unsigned short* Wf  = us;               //  262144 us (4 frag-packed weights)
    unsigned short* xT  = Wf  + 262144;     // 4194304 us
    unsigned short* qH  = xT  + 4194304;    // 4194304 us  [b][h][m][16]
    unsigned short* xsT = qH  + 4194304;    // 1048576 us
    unsigned short* kH  = xsT + 1048576;    // 1048576 us  [b][h][n][16]
    unsigned short* vbf = kH  + 1048576;    // 1048576 us  [b][c][n]
    unsigned short* aoH = vbf + 1048576;    // 4194304 us  [b][h][m][16]

    prep_k<<<1280, 256, 0, stream>>>(wq, wk, wv, wo, Wf, x, xT);
    gemm_k<HW, 0><<<dim3(4, 8, BATCH), 256, 0, stream>>>(
        Wf, xT, bq, nullptr, q, qH, nullptr, nullptr, nullptr, nullptr, nullptr);
    dwconv_k<<<BATCH * CH, 256, 0, stream>>>(q, off_dw_w, off_dw_b, off);
    lngs_k<<<BATCH * NS, 256, 0, stream>>>(off, ln_g, ln_b, off_pw_w, x, xsT);
    gemm_k<NS, 1><<<dim3(4, 2, 2 * BATCH), 256, 0, stream>>>(
        Wf + 65536, xsT, bk, bv, nullptr, kH, vbf, nullptr, nullptr, nullptr, nullptr);
    attn_mfma_k<<<BATCH * NH * 4, 256, 0, stream>>>(qH, kH, vbf, aoH);
    gemm_k<HW, 2><<<dim3(4, 8, BATCH), 256, 0, stream>>>(
        Wf + 3 * 65536, aoH, bo, nullptr, (float*)d_out, nullptr, nullptr,
        bn_g, bn_b, bn_m, bn_v);
}

// Round 14
// 110.635 us; speedup vs baseline: 3.5057x; 1.0100x over previous
//
#include <hip/hip_runtime.h>
#include <hip/hip_bf16.h>
#include <math.h>

#define BATCH 16
#define CH    256
#define HW    1024
#define NS    256
#define NH    16
#define DH    16

typedef __attribute__((ext_vector_type(8))) short short8v;
typedef __attribute__((ext_vector_type(4))) float float4v;

__device__ __forceinline__ unsigned short f2bf(float f) {
    return __builtin_bit_cast(unsigned short, __float2bfloat16(f));
}
__device__ __forceinline__ unsigned pack2(float lo, float hi) {
    return (unsigned)f2bf(lo) | ((unsigned)f2bf(hi) << 16);
}

// ---------------------------------------------------------------------------
// prep: blocks 0..1023   -> weight repack (4 matrices, A-frag order)
//       blocks 1024..1279 -> x[b][c][p] fp32 -> xT[b][p][c] bf16
// Wf[mat][((ot*8+kt)*64+l)*8+i] = W[ot*16+(l&15)][kt*32+8*(l>>4)+i]
// ---------------------------------------------------------------------------
__global__ __launch_bounds__(256) void prep_k(
    const float* __restrict__ wq, const float* __restrict__ wk,
    const float* __restrict__ wv, const float* __restrict__ wo,
    unsigned short* __restrict__ Wf,
    const float* __restrict__ x, unsigned short* __restrict__ xT)
{
    int blk = blockIdx.x;
    if (blk < 1024) {
        const float* W;
        switch (blk >> 8) {
            case 0: W = wq; break;
            case 1: W = wk; break;
            case 2: W = wv; break;
            default: W = wo; break;
        }
        int e = (blk & 255) * 256 + threadIdx.x;     // 0..65535
        int i = e & 7, l = (e >> 3) & 63, kt = (e >> 9) & 7, ot = e >> 12;
        float v = W[(ot * 16 + (l & 15)) * 256 + kt * 32 + 8 * (l >> 4) + i];
        Wf[(blk >> 8) * 65536 + e] = f2bf(v);
    } else {
        int xb = blk - 1024;                          // 0..255
        int b = xb >> 4, pblk = (xb >> 2) & 3, cblk = xb & 3;
        int p = pblk * 256 + threadIdx.x;
        const float* xp = x + (size_t)b * CH * HW + p;
        unsigned short* o = xT + ((size_t)b * HW + p) * CH;
        #pragma unroll
        for (int cc = 0; cc < 64; cc += 8) {
            int c0 = cblk * 64 + cc;
            short8v t;
            #pragma unroll
            for (int i = 0; i < 8; ++i) t[i] = (short)f2bf(xp[(size_t)(c0 + i) * HW]);
            *(short8v*)&o[c0] = t;
        }
    }
}

// ---------------------------------------------------------------------------
// bf16 MFMA GEMM conv1x1 (packed Wf): C[o][p] = W[o][:] . X[:][p]  (K=256)
// MODE 0: Q  -> outF fp32 [b][o][p] + outB bf16 qH [b][h][p][16] (pre-scaled 0.25)
// MODE 2: O  -> outF fp32 d_out with BN epilogue; XT is aoH [b][h][m][16]
// ---------------------------------------------------------------------------
template<int P, int MODE>
__global__ __launch_bounds__(256) void gemm_k(
    const unsigned short* __restrict__ Wf, const unsigned short* __restrict__ XT,
    const float* __restrict__ bias,
    float* __restrict__ outF, unsigned short* __restrict__ outB,
    const float* __restrict__ bn_g, const float* __restrict__ bn_b,
    const float* __restrict__ bn_m, const float* __restrict__ bn_v)
{
    const int b = blockIdx.z;

    const int t = threadIdx.x, lane = t & 63, wvi = t >> 6;
    const int g = lane >> 4, col = lane & 15;
    const int o0 = blockIdx.x * 64;
    const int p0 = blockIdx.y * 128 + wvi * 32;
    const unsigned short* xb = XT + ((size_t)b * P + p0) * CH;   // MODE 0

    float4v acc[4][2];
    #pragma unroll
    for (int mi = 0; mi < 4; ++mi)
        #pragma unroll
        for (int ni = 0; ni < 2; ++ni) {
            float4v z = {0.f, 0.f, 0.f, 0.f};
            acc[mi][ni] = z;
        }

    #pragma unroll
    for (int kt = 0; kt < 8; ++kt) {
        short8v af[4], bf[2];
        #pragma unroll
        for (int mi = 0; mi < 4; ++mi)
            af[mi] = *(const short8v*)&Wf[(((((o0 >> 4) + mi) * 8) + kt) * 64 + lane) * 8];
        #pragma unroll
        for (int ni = 0; ni < 2; ++ni) {
            if (MODE == 2) {
                // aoH head-major: channels kt*32+8g..+7 lie inside head hh
                const int hh = kt * 2 + (g >> 1);
                const int p  = p0 + ni * 16 + col;
                bf[ni] = *(const short8v*)&XT[(((size_t)(b * 16 + hh) * P + p) << 4) + 8 * (g & 1)];
            } else {
                bf[ni] = *(const short8v*)&xb[(size_t)(ni * 16 + col) * CH + kt * 32 + 8 * g];
            }
        }
        #pragma unroll
        for (int mi = 0; mi < 4; ++mi)
            #pragma unroll
            for (int ni = 0; ni < 2; ++ni)
                acc[mi][ni] = __builtin_amdgcn_mfma_f32_16x16x32_bf16(
                    af[mi], bf[ni], acc[mi][ni], 0, 0, 0);
    }

    #pragma unroll
    for (int mi = 0; mi < 4; ++mi) {
        const int ob = o0 + mi * 16 + 4 * g;
        float bs[4];
        #pragma unroll
        for (int ii = 0; ii < 4; ++ii) bs[ii] = bias[ob + ii];

        if (MODE == 2) {
            float sc[4], sh[4];
            #pragma unroll
            for (int ii = 0; ii < 4; ++ii) {
                int o = ob + ii;
                float s = bn_g[o] * rsqrtf(bn_v[o] + 1e-5f);
                sc[ii] = s;
                sh[ii] = bn_b[o] - bn_m[o] * s + bs[ii] * s;
            }
            #pragma unroll
            for (int ni = 0; ni < 2; ++ni) {
                int p = p0 + ni * 16 + col;
                #pragma unroll
                for (int ii = 0; ii < 4; ++ii)
                    outF[((size_t)(b * CH + ob + ii)) * P + p] =
                        acc[mi][ni][ii] * sc[ii] + sh[ii];
            }
        } else {
            const int hh = (o0 >> 4) + mi;     // head index (4g < 16)
            #pragma unroll
            for (int ni = 0; ni < 2; ++ni) {
                int p = p0 + ni * 16 + col;
                float v0 = acc[mi][ni][0] + bs[0];
                float v1 = acc[mi][ni][1] + bs[1];
                float v2 = acc[mi][ni][2] + bs[2];
                float v3 = acc[mi][ni][3] + bs[3];
                outF[((size_t)(b * CH + ob + 0)) * P + p] = v0;
                outF[((size_t)(b * CH + ob + 1)) * P + p] = v1;
                outF[((size_t)(b * CH + ob + 2)) * P + p] = v2;
                outF[((size_t)(b * CH + ob + 3)) * P + p] = v3;
                uint2 w;   // qH pre-scaled by 0.25 (exact pow2)
                w.x = pack2(v0 * 0.25f, v1 * 0.25f);
                w.y = pack2(v2 * 0.25f, v3 * 0.25f);
                *(uint2*)&outB[(((size_t)(b * 16 + hh) * P + p) << 4) + 4 * g] = w;
            }
        }
    }
}

// ---------------------------------------------------------------------------
// depthwise 9x9 conv, stride 2, pad 4 (q fp32 [b][c][32][32] -> off [b][c][16][16])
// ---------------------------------------------------------------------------
__global__ __launch_bounds__(256) void dwconv_k(
    const float* __restrict__ q, const float* __restrict__ w,
    const float* __restrict__ bias, float* __restrict__ off)
{
    int bc = blockIdx.x;
    int c  = bc & (CH - 1);
    __shared__ float plane[HW];
    __shared__ float kw[81];
    int t = threadIdx.x;
    const float* qp = q + (size_t)bc * HW;
    #pragma unroll
    for (int j = t; j < HW; j += 256) plane[j] = qp[j];
    if (t < 81) kw[t] = w[c * 81 + t];
    __syncthreads();
    int hk = t >> 4, wk = t & 15;
    float s = bias[c];
    int yb = hk * 2 - 4, xb = wk * 2 - 4;
    #pragma unroll
    for (int dy = 0; dy < 9; ++dy) {
        int yy = yb + dy;
        if ((unsigned)yy < 32u) {
            #pragma unroll
            for (int dx = 0; dx < 9; ++dx) {
                int xx = xb + dx;
                if ((unsigned)xx < 32u) s += kw[dy * 9 + dx] * plane[yy * 32 + xx];
            }
        }
    }
    off[(size_t)bc * NS + t] = s;
}

// ---------------------------------------------------------------------------
// fused: LN(channel) + GELU + projection + ref + tanh + bilinear grid sample
// -> xsT bf16 [b][s][c]
// ---------------------------------------------------------------------------
__device__ inline void block_reduce2(float& a, float& b, int t, float* sbuf)
{
    #pragma unroll
    for (int o = 32; o > 0; o >>= 1) {
        a += __shfl_down(a, o);
        b += __shfl_down(b, o);
    }
    int w = t >> 6;
    if ((t & 63) == 0) { sbuf[w * 2] = a; sbuf[w * 2 + 1] = b; }
    __syncthreads();
    a = sbuf[0] + sbuf[2] + sbuf[4] + sbuf[6];
    b = sbuf[1] + sbuf[3] + sbuf[5] + sbuf[7];
    __syncthreads();
}

__global__ __launch_bounds__(256) void lngs_k(
    const float* __restrict__ off, const float* __restrict__ ln_g,
    const float* __restrict__ ln_b, const float* __restrict__ pw,
    const float* __restrict__ x, unsigned short* __restrict__ xsT)
{
    __shared__ float sbuf[8];
    int bs = blockIdx.x;
    int b = bs >> 8, s = bs & 255;
    int c = threadIdx.x;
    float v = off[((size_t)(b * CH + c)) * NS + s];
    float a = v, q2 = v * v;
    block_reduce2(a, q2, c, sbuf);
    float mean = a * (1.0f / 256.0f);
    float var  = q2 * (1.0f / 256.0f) - mean * mean;
    float xn = (v - mean) * rsqrtf(var + 1e-5f) * ln_g[c] + ln_b[c];
    float g = 0.5f * xn * (1.0f + erff(xn * 0.70710678118654752f));
    float d0 = g * pw[c];
    float d1 = g * pw[CH + c];
    block_reduce2(d0, d1, c, sbuf);   // broadcasts sums to all threads

    int hk = s >> 4, wk = s & 15;
    float ry = ((hk + 0.5f) / 16.0f) * 2.0f - 1.0f;
    float rx = ((wk + 0.5f) / 16.0f) * 2.0f - 1.0f;
    float py = tanhf(d0 + ry);
    float px = tanhf(d1 + rx);

    float gx = (px + 1.0f) * 0.5f * 31.0f;
    float gy = (py + 1.0f) * 0.5f * 31.0f;
    float x0f = floorf(gx), y0f = floorf(gy);
    int ix = (int)x0f, iy = (int)y0f;
    float wx1 = gx - x0f, wx0 = 1.0f - wx1;
    float wy1 = gy - y0f, wy0 = 1.0f - wy1;
    const float* img = x + ((size_t)b * CH + c) * HW;
    float v00 = ((unsigned)iy < 32u && (unsigned)ix < 32u) ? img[iy * 32 + ix] : 0.0f;
    float v01 = ((unsigned)iy < 32u && (unsigned)(ix + 1) < 32u) ? img[iy * 32 + ix + 1] : 0.0f;
    float v10 = ((unsigned)(iy + 1) < 32u && (unsigned)ix < 32u) ? img[(iy + 1) * 32 + ix] : 0.0f;
    float v11 = ((unsigned)(iy + 1) < 32u && (unsigned)(ix + 1) < 32u) ? img[(iy + 1) * 32 + ix + 1] : 0.0f;
    float vv = wy0 * wx0 * v00 + wy0 * wx1 * v01 + wy1 * wx0 * v10 + wy1 * wx1 * v11;
    xsT[(size_t)bs * CH + c] = f2bf(vv);
}

// ---------------------------------------------------------------------------
// fused KV-build + MFMA attention. Grid = (b,h,mhalf): 512 blocks x 1024 thr
// (2 blocks/CU, full wave occupancy). Each of the 16 waves builds ONE K
// n-tile and ONE V n-tile from xsT + packed wk/wv (bit-identical MFMA/bias/
// f2bf sequence to the former standalone KV GEMM; fragment write-out maps
// HW-verified in R7/R12), directly into the compact QK A-frag Kp (stride-0
// zero trick) and the PV A-frag Vp (conflict-free, no swizzle). Then each
// wave runs the R13 attention body over its 32 query rows (head-major I/O).
// KV is built twice per head (once per mhalf) - negligible (~0.26 GFLOP).
// ---------------------------------------------------------------------------
__global__ __launch_bounds__(1024) void attn_fused_k(
    const unsigned short* __restrict__ qH, const unsigned short* __restrict__ xsT,
    const unsigned short* __restrict__ Wf,
    const float* __restrict__ bk, const float* __restrict__ bv,
    unsigned short* __restrict__ aoH)
{
    const int bh    = blockIdx.x >> 1;
    const int mhalf = blockIdx.x & 1;
    const int b = bh >> 4, h = bh & 15;

    __shared__ short Kp[16 * 32 * 8 + 8];   // 8KB + 16B zero slot (QK A-frag)
    __shared__ short Vp[8 * 64 * 8];        // 8KB PV A-frag (8 chunks of n=32)
    __shared__ short Ps[16][16 * 32];       // 16KB per-wave P scratch

    const int tid  = threadIdx.x;
    const int lane = tid & 63;
    const int wvi  = tid >> 6;      // 0..15
    const int col  = lane & 15;
    const int g    = lane >> 4;

    // ---- build K, V: wave wvi builds n-tile t = wvi (R7/R12-verified) ----
    {
        const unsigned short* WfK = Wf + 1 * 65536 + h * 4096;  // wk tiles, ot=h
        const unsigned short* WfV = Wf + 2 * 65536 + h * 4096;  // wv tiles, ot=h
        float bk4[4];
        #pragma unroll
        for (int j = 0; j < 4; ++j) bk4[j] = bk[h * 16 + 4 * g + j];
        const float bvv = bv[h * 16 + col];

        const int t  = wvi;
        const int n0 = t * 16;
        float4v accK = {0.f, 0.f, 0.f, 0.f};
        float4v accV = {0.f, 0.f, 0.f, 0.f};
        #pragma unroll
        for (int kt = 0; kt < 8; ++kt) {
            short8v xsf = *(const short8v*)&xsT[((size_t)(b * NS + n0 + col)) * CH + kt * 32 + 8 * g];
            short8v wkf = *(const short8v*)&WfK[(kt * 64 + lane) * 8];
            short8v wvf = *(const short8v*)&WfV[(kt * 64 + lane) * 8];
            accK = __builtin_amdgcn_mfma_f32_16x16x32_bf16(wkf, xsf, accK, 0, 0, 0);
            accV = __builtin_amdgcn_mfma_f32_16x16x32_bf16(xsf, wvf, accV, 0, 0, 0);
        }
        uint2 wrk;
        wrk.x = pack2(accK[0] + bk4[0], accK[1] + bk4[1]);
        wrk.y = pack2(accK[2] + bk4[2], accK[3] + bk4[3]);
        *(uint2*)&Kp[(t * 32 + (g >> 1) * 16 + col) * 8 + 4 * (g & 1)] = wrk;
        uint2 wrv;
        wrv.x = pack2(accV[0] + bvv, accV[1] + bvv);
        wrv.y = pack2(accV[2] + bvv, accV[3] + bvv);
        *(uint2*)&Vp[((t >> 1) * 64 + col + 16 * ((2 * t + (g >> 1)) & 3)) * 8 + 4 * (g & 1)] = wrv;
    }
    if (tid == 0) {
        short8v z = {0, 0, 0, 0, 0, 0, 0, 0};
        *(short8v*)&Kp[16 * 32 * 8] = z;
    }
    __syncthreads();

    const unsigned short* Qb = qH + ((size_t)(b * 16 + h) * HW << 4);
    unsigned short*       Ob = aoH + ((size_t)(b * 16 + h) * HW << 4);
    char* pbase = (char*)Ps[wvi];
    // stride-0 zero trick for the padded d=16..31 half of the QK A operand
    const char* kbase = (const char*)Kp + ((lane < 32) ? lane * 16 : 16 * 32 * 16);
    const int   kstep = (lane < 32) ? 512 : 0;

    #pragma unroll
    for (int mt = 0; mt < 2; ++mt) {
        const int m0 = mhalf * 512 + wvi * 32 + mt * 16;

        short8v qf = {0, 0, 0, 0, 0, 0, 0, 0};
        if (g < 2)
            qf = *(const short8v*)&Qb[((m0 + col) << 4) + 8 * g];

        float4v p[16];
        #pragma unroll
        for (int t = 0; t < 16; ++t) {
            short8v kf = *(const short8v*)(kbase + t * kstep);
            float4v z = {0.f, 0.f, 0.f, 0.f};
            p[t] = __builtin_amdgcn_mfma_f32_16x16x32_bf16(kf, qf, z, 0, 0, 0);
        }

        // tree max (bit-exact reassociation of fmax)
        float mx4[16];
        #pragma unroll
        for (int t = 0; t < 16; ++t)
            mx4[t] = fmaxf(fmaxf(p[t][0], p[t][1]), fmaxf(p[t][2], p[t][3]));
        #pragma unroll
        for (int o = 8; o >= 1; o >>= 1)
            #pragma unroll
            for (int i = 0; i < 8; ++i)
                if (i < o) mx4[i] = fmaxf(mx4[i], mx4[i + o]);
        float mx = mx4[0];
        mx = fmaxf(mx, __shfl_xor(mx, 16));
        mx = fmaxf(mx, __shfl_xor(mx, 32));

        float s4[4] = {0.f, 0.f, 0.f, 0.f};
        #pragma unroll
        for (int t = 0; t < 16; ++t) {
            #pragma unroll
            for (int i = 0; i < 4; ++i) {
                float e = __expf(p[t][i] - mx);   // 0.25 pre-folded into qH
                p[t][i] = e;
                s4[i] += e;
            }
        }
        float sum = (s4[0] + s4[1]) + (s4[2] + s4[3]);
        sum += __shfl_xor(sum, 16);
        sum += __shfl_xor(sum, 32);
        const float inv = 1.0f / sum;

        float4v acc = {0.f, 0.f, 0.f, 0.f};
        #pragma unroll
        for (int c = 0; c < 8; ++c) {
            #pragma unroll
            for (int pp = 0; pp < 2; ++pp) {
                float4v pv = p[2 * c + pp];
                uint2 wr;
                wr.x = pack2(pv[0], pv[1]);
                wr.y = pack2(pv[2], pv[3]);
                *(uint2*)(pbase + ((col * 64 + (16 * pp + 4 * g) * 2) ^ ((col & 7) << 4))) = wr;
            }
            short8v pf = *(const short8v*)(pbase + ((col * 64 + 16 * g) ^ ((col & 7) << 4)));
            short8v vf = *(const short8v*)&Vp[(c * 64 + lane) * 8];
            acc = __builtin_amdgcn_mfma_f32_16x16x32_bf16(vf, pf, acc, 0, 0, 0);
        }

        uint2 w;
        w.x = pack2(acc[0] * inv, acc[1] * inv);
        w.y = pack2(acc[2] * inv, acc[3] * inv);
        *(uint2*)&Ob[((m0 + col) << 4) + 4 * g] = w;
    }
}

// ---------------------------------------------------------------------------
extern "C" void kernel_launch(void* const* d_in, const int* in_sizes, int n_in,
                              void* d_out, int out_size, void* d_ws, size_t ws_size,
                              hipStream_t stream)
{
    const float* x        = (const float*)d_in[0];
    const float* wq       = (const float*)d_in[1];
    const float* bq       = (const float*)d_in[2];
    const float* off_dw_w = (const float*)d_in[3];
    const float* off_dw_b = (const float*)d_in[4];
    const float* ln_g     = (const float*)d_in[5];
    const float* ln_b     = (const float*)d_in[6];
    const float* off_pw_w = (const float*)d_in[7];
    const float* wk       = (const float*)d_in[8];
    const float* bk       = (const float*)d_in[9];
    const float* wv       = (const float*)d_in[10];
    const float* bv       = (const float*)d_in[11];
    const float* wo       = (const float*)d_in[12];
    const float* bo       = (const float*)d_in[13];
    const float* bn_g     = (const float*)d_in[14];
    const float* bn_b     = (const float*)d_in[15];
    const float* bn_m     = (const float*)d_in[16];
    const float* bn_v     = (const float*)d_in[17];

    float* ws  = (float*)d_ws;
    float* q   = ws;                        // 4194304 f (fp32 for dwconv)
    float* off = q + 4194304;               // 1048576 f
    unsigned short* us  = (unsigned short*)(off + 1048576);
    unsigned short* Wf  = us;               //  262144 us (4 frag-packed weights)
    unsigned short* xT  = Wf  + 262144;     // 4194304 us
    unsigned short* qH  = xT  + 4194304;    // 4194304 us  [b][h][m][16]
    unsigned short* xsT = qH  + 4194304;    // 1048576 us
    unsigned short* aoH = xsT + 1048576;    // 4194304 us  [b][h][m][16]

    prep_k<<<1280, 256, 0, stream>>>(wq, wk, wv, wo, Wf, x, xT);
    gemm_k<HW, 0><<<dim3(4, 8, BATCH), 256, 0, stream>>>(
        Wf, xT, bq, q, qH, nullptr, nullptr, nullptr, nullptr);
    dwconv_k<<<BATCH * CH, 256, 0, stream>>>(q, off_dw_w, off_dw_b, off);
    lngs_k<<<BATCH * NS, 256, 0, stream>>>(off, ln_g, ln_b, off_pw_w, x, xsT);
    attn_fused_k<<<BATCH * NH * 2, 1024, 0, stream>>>(qH, xsT, Wf, bk, bv, aoH);
    gemm_k<HW, 2><<<dim3(4, 8, BATCH), 256, 0, stream>>>(
        Wf + 3 * 65536, aoH, bo, (float*)d_out, nullptr,
        bn_g, bn_b, bn_m, bn_v);
}